// Round 1
// baseline (335.662 us; speedup 1.0000x reference)
//
#include <hip/hip_runtime.h>
#include <math.h>

// ManifoldHyperConnectionFuse on MI355X.
// B=8, L=4096, N=4, D=256 -> 32768 tokens of 1024 floats.
// Per token: H = (alpha-scaled nw .* hf) @ w  (1024->24),
//            r_ = 1/(||hf||/32 + 1e-6), sigmoids, K=exp(...), Sinkhorn(10),
//            out[n][d] = H_post[n]*h_pre[d] + sum_m P[n][m]*h[m][d].
//
// Block = 256 threads (4 waves), 16 tokens per block, grid = 2048.
// Thread (lane s, wave gg): owns w2r[k][j] = alpha_sel(g)*nw[i]*w[i,g],
//   i = 16*s+k (k<16), g = 6*gg+j (j<6)  -> 96 VGPRs, loaded once per block.
// Reduction: 6 accumulators per wave, 64-lane xor-butterfly (wave gg covers
// all 1024 i for its 6 g's). Sinkhorn: wave 0, whole-wave redundant.

#define NTOK 16

__device__ __forceinline__ float sigmoid_f(float z) {
    return 1.0f / (1.0f + __expf(-z));
}

__global__ __launch_bounds__(256)
void mhc_kernel(const float* __restrict__ h,
                const float* __restrict__ nw,
                const float* __restrict__ w,
                const float* __restrict__ alpha,
                const float* __restrict__ beta,
                float* __restrict__ out)
{
    const int tid  = threadIdx.x;
    const int lane = tid & 63;
    const int gg   = tid >> 6;   // wave id 0..3

    __shared__ float Hpart[24];
    __shared__ float smalls[24]; // [0:4) Hpre, [4:8) Hpost, [8:24) P row-major

    const float a0 = alpha[0], a1 = alpha[1], a2 = alpha[2];

    // ---- one-time per block: fold alpha*nw into register-resident w tile ----
    float w2r[16][6];
    #pragma unroll
    for (int k = 0; k < 16; ++k) {
        const int i = 16 * lane + k;
        const float nwk = nw[i];
        #pragma unroll
        for (int j = 0; j < 6; ++j) {
            const int g = 6 * gg + j;
            const float as = (g < 4) ? a0 : ((g < 8) ? a1 : a2);
            w2r[k][j] = as * nwk * w[i * 24 + g];
        }
    }

    const long tok0 = (long)blockIdx.x * NTOK;

    // prefetch token 0's phase-A slice: h[tok, 16*lane .. 16*lane+15]
    float4 xa0, xa1, xa2, xa3;
    {
        const float* p = h + tok0 * 1024 + lane * 16;
        xa0 = *(const float4*)(p + 0);
        xa1 = *(const float4*)(p + 4);
        xa2 = *(const float4*)(p + 8);
        xa3 = *(const float4*)(p + 12);
    }

    for (int it = 0; it < NTOK; ++it) {
        const long tok = tok0 + it;
        const float* htok = h + tok * 1024;

        float x[16];
        x[0]=xa0.x;  x[1]=xa0.y;  x[2]=xa0.z;  x[3]=xa0.w;
        x[4]=xa1.x;  x[5]=xa1.y;  x[6]=xa1.z;  x[7]=xa1.w;
        x[8]=xa2.x;  x[9]=xa2.y;  x[10]=xa2.z; x[11]=xa2.w;
        x[12]=xa3.x; x[13]=xa3.y; x[14]=xa3.z; x[15]=xa3.w;

        // prefetch next token (latency hides under this token's compute)
        if (it + 1 < NTOK) {
            const float* p = htok + 1024 + lane * 16;
            xa0 = *(const float4*)(p + 0);
            xa1 = *(const float4*)(p + 4);
            xa2 = *(const float4*)(p + 8);
            xa3 = *(const float4*)(p + 12);
        }

        // ---- phase A: matvec partials (96 FMA) + ||hf||^2 (wave 0) ----
        float acc[6] = {0.f, 0.f, 0.f, 0.f, 0.f, 0.f};
        #pragma unroll
        for (int k = 0; k < 16; ++k) {
            const float xv = x[k];
            acc[0] = fmaf(xv, w2r[k][0], acc[0]);
            acc[1] = fmaf(xv, w2r[k][1], acc[1]);
            acc[2] = fmaf(xv, w2r[k][2], acc[2]);
            acc[3] = fmaf(xv, w2r[k][3], acc[3]);
            acc[4] = fmaf(xv, w2r[k][4], acc[4]);
            acc[5] = fmaf(xv, w2r[k][5], acc[5]);
        }
        float r2 = 0.f;
        if (gg == 0) {
            #pragma unroll
            for (int k = 0; k < 16; ++k) r2 = fmaf(x[k], x[k], r2);
        }

        // 64-lane xor-butterfly: each wave reduces its 6 g-values over all i
        #pragma unroll
        for (int off = 1; off < 64; off <<= 1) {
            acc[0] += __shfl_xor(acc[0], off);
            acc[1] += __shfl_xor(acc[1], off);
            acc[2] += __shfl_xor(acc[2], off);
            acc[3] += __shfl_xor(acc[3], off);
            acc[4] += __shfl_xor(acc[4], off);
            acc[5] += __shfl_xor(acc[5], off);
        }
        if (gg == 0) {
            #pragma unroll
            for (int off = 1; off < 64; off <<= 1) r2 += __shfl_xor(r2, off);
        }

        if (lane == 0) {
            #pragma unroll
            for (int j = 0; j < 6; ++j) Hpart[6 * gg + j] = acc[j];
        }
        __syncthreads();

        // ---- wave 0: small-vector math + Sinkhorn (whole-wave redundant) ----
        if (gg == 0) {
            const float r_ = 1.0f / (sqrtf(r2) * 0.03125f + 1e-6f);
            float Hpre[4], Hpost[4], K[16];
            #pragma unroll
            for (int n = 0; n < 4; ++n)
                Hpre[n] = sigmoid_f(fmaf(r_, Hpart[n], beta[n]));
            #pragma unroll
            for (int n = 0; n < 4; ++n)
                Hpost[n] = 2.0f * sigmoid_f(fmaf(r_, Hpart[4 + n], beta[4 + n]));
            #pragma unroll
            for (int q = 0; q < 16; ++q)
                K[q] = __expf(fmaf(r_, Hpart[8 + q], beta[8 + q]));

            float u0=1.f,u1=1.f,u2=1.f,u3=1.f;
            float v0=1.f,v1=1.f,v2=1.f,v3=1.f;
            for (int itr = 0; itr < 10; ++itr) {
                u0 = 1.0f/(K[0]*v0  + K[1]*v1  + K[2]*v2  + K[3]*v3  + 1e-8f);
                u1 = 1.0f/(K[4]*v0  + K[5]*v1  + K[6]*v2  + K[7]*v3  + 1e-8f);
                u2 = 1.0f/(K[8]*v0  + K[9]*v1  + K[10]*v2 + K[11]*v3 + 1e-8f);
                u3 = 1.0f/(K[12]*v0 + K[13]*v1 + K[14]*v2 + K[15]*v3 + 1e-8f);
                v0 = 1.0f/(K[0]*u0  + K[4]*u1  + K[8]*u2  + K[12]*u3 + 1e-8f);
                v1 = 1.0f/(K[1]*u0  + K[5]*u1  + K[9]*u2  + K[13]*u3 + 1e-8f);
                v2 = 1.0f/(K[2]*u0  + K[6]*u1  + K[10]*u2 + K[14]*u3 + 1e-8f);
                v3 = 1.0f/(K[3]*u0  + K[7]*u1  + K[11]*u2 + K[15]*u3 + 1e-8f);
            }
            if (lane == 0) {
                smalls[0] = Hpre[0];  smalls[1] = Hpre[1];
                smalls[2] = Hpre[2];  smalls[3] = Hpre[3];
                smalls[4] = Hpost[0]; smalls[5] = Hpost[1];
                smalls[6] = Hpost[2]; smalls[7] = Hpost[3];
                smalls[8]  = u0*K[0]*v0;   smalls[9]  = u0*K[1]*v1;
                smalls[10] = u0*K[2]*v2;   smalls[11] = u0*K[3]*v3;
                smalls[12] = u1*K[4]*v0;   smalls[13] = u1*K[5]*v1;
                smalls[14] = u1*K[6]*v2;   smalls[15] = u1*K[7]*v3;
                smalls[16] = u2*K[8]*v0;   smalls[17] = u2*K[9]*v1;
                smalls[18] = u2*K[10]*v2;  smalls[19] = u2*K[11]*v3;
                smalls[20] = u3*K[12]*v0;  smalls[21] = u3*K[13]*v1;
                smalls[22] = u3*K[14]*v2;  smalls[23] = u3*K[15]*v3;
            }
        }
        __syncthreads();

        // ---- phase C: output. thread(lane,gg): n = gg, d = 4*lane..+3 ----
        {
            const float hp0 = smalls[0], hp1 = smalls[1];
            const float hp2 = smalls[2], hp3 = smalls[3];
            const float hpost = smalls[4 + gg];
            const float P0 = smalls[8 + 4*gg + 0];
            const float P1 = smalls[8 + 4*gg + 1];
            const float P2 = smalls[8 + 4*gg + 2];
            const float P3 = smalls[8 + 4*gg + 3];

            const float* pm = htok + 4 * lane;      // L1-resident re-read
            const float4 xm0 = *(const float4*)(pm);
            const float4 xm1 = *(const float4*)(pm + 256);
            const float4 xm2 = *(const float4*)(pm + 512);
            const float4 xm3 = *(const float4*)(pm + 768);

            float4 o;
            {
                const float hpre = hp0*xm0.x + hp1*xm1.x + hp2*xm2.x + hp3*xm3.x;
                o.x = fmaf(hpost, hpre, P0*xm0.x + P1*xm1.x + P2*xm2.x + P3*xm3.x);
            }
            {
                const float hpre = hp0*xm0.y + hp1*xm1.y + hp2*xm2.y + hp3*xm3.y;
                o.y = fmaf(hpost, hpre, P0*xm0.y + P1*xm1.y + P2*xm2.y + P3*xm3.y);
            }
            {
                const float hpre = hp0*xm0.z + hp1*xm1.z + hp2*xm2.z + hp3*xm3.z;
                o.z = fmaf(hpost, hpre, P0*xm0.z + P1*xm1.z + P2*xm2.z + P3*xm3.z);
            }
            {
                const float hpre = hp0*xm0.w + hp1*xm1.w + hp2*xm2.w + hp3*xm3.w;
                o.w = fmaf(hpost, hpre, P0*xm0.w + P1*xm1.w + P2*xm2.w + P3*xm3.w);
            }
            *(float4*)(out + tok * 1024 + gg * 256 + 4 * lane) = o;
        }
    }
}

extern "C" void kernel_launch(void* const* d_in, const int* in_sizes, int n_in,
                              void* d_out, int out_size, void* d_ws, size_t ws_size,
                              hipStream_t stream) {
    const float* h     = (const float*)d_in[0];
    const float* nw    = (const float*)d_in[1];
    const float* w     = (const float*)d_in[2];
    const float* alpha = (const float*)d_in[3];
    const float* beta  = (const float*)d_in[4];
    float* out = (float*)d_out;

    // 32768 tokens / 16 per block = 2048 blocks of 256 threads
    mhc_kernel<<<2048, 256, 0, stream>>>(h, nw, w, alpha, beta, out);
}

// Round 2
// 122.426 us; speedup vs baseline: 2.7418x; 2.7418x over previous
//
#include <hip/hip_runtime.h>
#include <math.h>

// ManifoldHyperConnectionFuse on MI355X — R1: amortized scalar phase.
// B=8, L=4096, N=4, D=256 -> 32768 tokens of 1024 floats.
//
// Block = 256 threads (4 waves), 16 tokens per block, grid = 2048.
// Phase A (no barriers): per token, thread (lane s, wave gg) computes
//   partial H[g], g=6gg..6gg+5 from its 16 i-rows (w2r register tile),
//   64-lane butterfly, lane0 writes to LDS Hpart[tok][26].
// ONE barrier. Scalar phase: lanes 0..15 of wave 0, lane t = token t:
//   full sigmoid/exp/Sinkhorn chain in registers (16 tokens in parallel,
//   serial chain paid once per block instead of 16x).
// ONE barrier. Phase C (no barriers): out[n][d] = Hpost[n]*h_pre[d] + P@h.

#define NTOK 16

__device__ __forceinline__ float sigmoid_f(float z) {
    return 1.0f / (1.0f + __expf(-z));
}

__global__ __launch_bounds__(256)
void mhc_kernel(const float* __restrict__ h,
                const float* __restrict__ nw,
                const float* __restrict__ w,
                const float* __restrict__ alpha,
                const float* __restrict__ beta,
                float* __restrict__ out)
{
    const int tid  = threadIdx.x;
    const int lane = tid & 63;
    const int gg   = tid >> 6;   // wave id 0..3

    __shared__ float Hpart[NTOK][26];  // [0:24) H partials, [24] r2; pad 26
    __shared__ float smalls[NTOK][26]; // [0:4) Hpre, [4:8) Hpost, [8:24) P

    const float a0 = alpha[0], a1 = alpha[1], a2 = alpha[2];

    // ---- one-time per block: fold alpha*nw into register-resident w tile ----
    float w2r[16][6];
    #pragma unroll
    for (int k = 0; k < 16; ++k) {
        const int i = 16 * lane + k;
        const float nwk = nw[i];
        #pragma unroll
        for (int j = 0; j < 6; ++j) {
            const int g = 6 * gg + j;
            const float as = (g < 4) ? a0 : ((g < 8) ? a1 : a2);
            w2r[k][j] = as * nwk * w[i * 24 + g];
        }
    }

    const long tok0 = (long)blockIdx.x * NTOK;

    // prefetch token 0's phase-A slice: h[tok, 16*lane .. 16*lane+15]
    float4 xa0, xa1, xa2, xa3;
    {
        const float* p = h + tok0 * 1024 + lane * 16;
        xa0 = *(const float4*)(p + 0);
        xa1 = *(const float4*)(p + 4);
        xa2 = *(const float4*)(p + 8);
        xa3 = *(const float4*)(p + 12);
    }

    // =================== phase A: all 16 tokens, no barriers ===============
    for (int it = 0; it < NTOK; ++it) {
        const float* htok = h + (tok0 + it) * 1024;

        float x[16];
        x[0]=xa0.x;  x[1]=xa0.y;  x[2]=xa0.z;  x[3]=xa0.w;
        x[4]=xa1.x;  x[5]=xa1.y;  x[6]=xa1.z;  x[7]=xa1.w;
        x[8]=xa2.x;  x[9]=xa2.y;  x[10]=xa2.z; x[11]=xa2.w;
        x[12]=xa3.x; x[13]=xa3.y; x[14]=xa3.z; x[15]=xa3.w;

        if (it + 1 < NTOK) {   // prefetch next token
            const float* p = htok + 1024 + lane * 16;
            xa0 = *(const float4*)(p + 0);
            xa1 = *(const float4*)(p + 4);
            xa2 = *(const float4*)(p + 8);
            xa3 = *(const float4*)(p + 12);
        }

        float acc[6] = {0.f, 0.f, 0.f, 0.f, 0.f, 0.f};
        #pragma unroll
        for (int k = 0; k < 16; ++k) {
            const float xv = x[k];
            acc[0] = fmaf(xv, w2r[k][0], acc[0]);
            acc[1] = fmaf(xv, w2r[k][1], acc[1]);
            acc[2] = fmaf(xv, w2r[k][2], acc[2]);
            acc[3] = fmaf(xv, w2r[k][3], acc[3]);
            acc[4] = fmaf(xv, w2r[k][4], acc[4]);
            acc[5] = fmaf(xv, w2r[k][5], acc[5]);
        }
        float r2 = 0.f;
        if (gg == 0) {
            #pragma unroll
            for (int k = 0; k < 16; ++k) r2 = fmaf(x[k], x[k], r2);
        }

        #pragma unroll
        for (int off = 1; off < 64; off <<= 1) {
            acc[0] += __shfl_xor(acc[0], off);
            acc[1] += __shfl_xor(acc[1], off);
            acc[2] += __shfl_xor(acc[2], off);
            acc[3] += __shfl_xor(acc[3], off);
            acc[4] += __shfl_xor(acc[4], off);
            acc[5] += __shfl_xor(acc[5], off);
        }
        if (gg == 0) {
            #pragma unroll
            for (int off = 1; off < 64; off <<= 1) r2 += __shfl_xor(r2, off);
        }

        if (lane == 0) {
            #pragma unroll
            for (int j = 0; j < 6; ++j) Hpart[it][6 * gg + j] = acc[j];
            if (gg == 0) Hpart[it][24] = r2;
        }
    }
    __syncthreads();

    // ====== scalar phase: lanes 0..15 of wave 0, one token per lane ========
    if (tid < NTOK) {
        const int t = tid;
        float Hp[24];
        #pragma unroll
        for (int q = 0; q < 24; ++q) Hp[q] = Hpart[t][q];
        const float r2v = Hpart[t][24];
        const float r_ = 1.0f / (sqrtf(r2v) * 0.03125f + 1e-6f);

        float Hpre[4], Hpost[4], K[16];
        #pragma unroll
        for (int n = 0; n < 4; ++n)
            Hpre[n] = sigmoid_f(fmaf(r_, Hp[n], beta[n]));
        #pragma unroll
        for (int n = 0; n < 4; ++n)
            Hpost[n] = 2.0f * sigmoid_f(fmaf(r_, Hp[4 + n], beta[4 + n]));
        #pragma unroll
        for (int q = 0; q < 16; ++q)
            K[q] = __expf(fmaf(r_, Hp[8 + q], beta[8 + q]));

        float u0=1.f,u1=1.f,u2=1.f,u3=1.f;
        float v0=1.f,v1=1.f,v2=1.f,v3=1.f;
        for (int itr = 0; itr < 10; ++itr) {
            u0 = 1.0f/(K[0]*v0  + K[1]*v1  + K[2]*v2  + K[3]*v3  + 1e-8f);
            u1 = 1.0f/(K[4]*v0  + K[5]*v1  + K[6]*v2  + K[7]*v3  + 1e-8f);
            u2 = 1.0f/(K[8]*v0  + K[9]*v1  + K[10]*v2 + K[11]*v3 + 1e-8f);
            u3 = 1.0f/(K[12]*v0 + K[13]*v1 + K[14]*v2 + K[15]*v3 + 1e-8f);
            v0 = 1.0f/(K[0]*u0  + K[4]*u1  + K[8]*u2  + K[12]*u3 + 1e-8f);
            v1 = 1.0f/(K[1]*u0  + K[5]*u1  + K[9]*u2  + K[13]*u3 + 1e-8f);
            v2 = 1.0f/(K[2]*u0  + K[6]*u1  + K[10]*u2 + K[14]*u3 + 1e-8f);
            v3 = 1.0f/(K[3]*u0  + K[7]*u1  + K[11]*u2 + K[15]*u3 + 1e-8f);
        }
        smalls[t][0] = Hpre[0];  smalls[t][1] = Hpre[1];
        smalls[t][2] = Hpre[2];  smalls[t][3] = Hpre[3];
        smalls[t][4] = Hpost[0]; smalls[t][5] = Hpost[1];
        smalls[t][6] = Hpost[2]; smalls[t][7] = Hpost[3];
        smalls[t][8]  = u0*K[0]*v0;   smalls[t][9]  = u0*K[1]*v1;
        smalls[t][10] = u0*K[2]*v2;   smalls[t][11] = u0*K[3]*v3;
        smalls[t][12] = u1*K[4]*v0;   smalls[t][13] = u1*K[5]*v1;
        smalls[t][14] = u1*K[6]*v2;   smalls[t][15] = u1*K[7]*v3;
        smalls[t][16] = u2*K[8]*v0;   smalls[t][17] = u2*K[9]*v1;
        smalls[t][18] = u2*K[10]*v2;  smalls[t][19] = u2*K[11]*v3;
        smalls[t][20] = u3*K[12]*v0;  smalls[t][21] = u3*K[13]*v1;
        smalls[t][22] = u3*K[14]*v2;  smalls[t][23] = u3*K[15]*v3;
    }
    __syncthreads();

    // =================== phase C: all 16 tokens, no barriers ===============
    // thread(lane,gg): n = gg, d = 4*lane..4*lane+3
    float4 ym0, ym1, ym2, ym3;
    {
        const float* p = h + tok0 * 1024 + 4 * lane;
        ym0 = *(const float4*)(p);
        ym1 = *(const float4*)(p + 256);
        ym2 = *(const float4*)(p + 512);
        ym3 = *(const float4*)(p + 768);
    }

    for (int it = 0; it < NTOK; ++it) {
        const long tok = tok0 + it;

        const float4 xm0 = ym0, xm1 = ym1, xm2 = ym2, xm3 = ym3;
        if (it + 1 < NTOK) {   // prefetch next token
            const float* p = h + (tok + 1) * 1024 + 4 * lane;
            ym0 = *(const float4*)(p);
            ym1 = *(const float4*)(p + 256);
            ym2 = *(const float4*)(p + 512);
            ym3 = *(const float4*)(p + 768);
        }

        const float hp0 = smalls[it][0], hp1 = smalls[it][1];
        const float hp2 = smalls[it][2], hp3 = smalls[it][3];
        const float hpost = smalls[it][4 + gg];
        const float P0 = smalls[it][8 + 4*gg + 0];
        const float P1 = smalls[it][8 + 4*gg + 1];
        const float P2 = smalls[it][8 + 4*gg + 2];
        const float P3 = smalls[it][8 + 4*gg + 3];

        float4 o;
        {
            const float hpre = hp0*xm0.x + hp1*xm1.x + hp2*xm2.x + hp3*xm3.x;
            o.x = fmaf(hpost, hpre, P0*xm0.x + P1*xm1.x + P2*xm2.x + P3*xm3.x);
        }
        {
            const float hpre = hp0*xm0.y + hp1*xm1.y + hp2*xm2.y + hp3*xm3.y;
            o.y = fmaf(hpost, hpre, P0*xm0.y + P1*xm1.y + P2*xm2.y + P3*xm3.y);
        }
        {
            const float hpre = hp0*xm0.z + hp1*xm1.z + hp2*xm2.z + hp3*xm3.z;
            o.z = fmaf(hpost, hpre, P0*xm0.z + P1*xm1.z + P2*xm2.z + P3*xm3.z);
        }
        {
            const float hpre = hp0*xm0.w + hp1*xm1.w + hp2*xm2.w + hp3*xm3.w;
            o.w = fmaf(hpost, hpre, P0*xm0.w + P1*xm1.w + P2*xm2.w + P3*xm3.w);
        }
        *(float4*)(out + tok * 1024 + gg * 256 + 4 * lane) = o;
    }
}

extern "C" void kernel_launch(void* const* d_in, const int* in_sizes, int n_in,
                              void* d_out, int out_size, void* d_ws, size_t ws_size,
                              hipStream_t stream) {
    const float* h     = (const float*)d_in[0];
    const float* nw    = (const float*)d_in[1];
    const float* w     = (const float*)d_in[2];
    const float* alpha = (const float*)d_in[3];
    const float* beta  = (const float*)d_in[4];
    float* out = (float*)d_out;

    mhc_kernel<<<2048, 256, 0, stream>>>(h, nw, w, alpha, beta, out);
}

// Round 3
// 113.155 us; speedup vs baseline: 2.9664x; 1.0819x over previous
//
#include <hip/hip_runtime.h>
#include <math.h>

// ManifoldHyperConnectionFuse on MI355X — R2: force register-resident weights.
// B=8, L=4096, N=4, D=256 -> 32768 tokens of 1024 floats.
//
// R1 post-mortem: VGPR=80 proved the compiler sank the folded-weight loads
// into the token loop (~3.2 GB of L2 reads). R2 pins them in VGPRs:
//   __launch_bounds__(256,3) (cap 170 VGPR) + asm keep-alive on all 96.
// Also: phase A i-partition changed to the coalesced pattern
//   i = 256q + 4*lane + r  -> every global load inst is a contiguous 1 KB
// wave access, and phase A / phase C per-lane addresses coincide (L1-hot).
//
// Block = 256 threads (4 waves), 16 tokens, grid = 2048.
// Phase A (no barriers): matvec partials via register weights + butterfly.
// 1 barrier. Scalar phase: lanes 0..15 of wave 0, token t = lane t.
// 1 barrier. Phase C (no barriers): out = Hpost*h_pre + P@h, 2-deep pipeline.

#define NTOK 16

__device__ __forceinline__ float sigmoid_f(float z) {
    return 1.0f / (1.0f + __expf(-z));
}

__global__ __launch_bounds__(256, 3)
void mhc_kernel(const float* __restrict__ h,
                const float* __restrict__ nw,
                const float* __restrict__ w,
                const float* __restrict__ alpha,
                const float* __restrict__ beta,
                float* __restrict__ out)
{
    const int tid  = threadIdx.x;
    const int lane = tid & 63;
    const int gg   = tid >> 6;   // wave id 0..3

    __shared__ float Hpart[NTOK][26];  // [0:24) H partials, [24] r2
    __shared__ float smalls[NTOK][26]; // [0:4) Hpre, [4:8) Hpost, [8:24) P

    const float a0 = alpha[0], a1 = alpha[1], a2 = alpha[2];

    // ---- one-time: fold alpha*nw*w into register tile, i = 256q+4*lane+r ----
    float w2r[16][6];
    #pragma unroll
    for (int q = 0; q < 4; ++q) {
        #pragma unroll
        for (int r = 0; r < 4; ++r) {
            const int k = 4 * q + r;
            const int i = 256 * q + 4 * lane + r;
            const float nwk = nw[i];
            #pragma unroll
            for (int j = 0; j < 6; ++j) {
                const int g = 6 * gg + j;
                const float as = (g < 4) ? a0 : ((g < 8) ? a1 : a2);
                w2r[k][j] = as * nwk * w[i * 24 + g];
            }
        }
    }
    // pin all 96 folded weights in VGPRs: prevents the compiler from
    // rematerializing (re-loading) them inside the token loop (R1 bug).
    #pragma unroll
    for (int k = 0; k < 16; ++k) {
        #pragma unroll
        for (int j = 0; j < 6; ++j) {
            asm volatile("" : "+v"(w2r[k][j]));
        }
    }

    const long tok0 = (long)blockIdx.x * NTOK;
    const float* p0 = h + tok0 * 1024 + 4 * lane;

    // prefetch token 0: float4 at p0 + {0,256,512,768}
    float4 xa0 = *(const float4*)(p0);
    float4 xa1 = *(const float4*)(p0 + 256);
    float4 xa2 = *(const float4*)(p0 + 512);
    float4 xa3 = *(const float4*)(p0 + 768);

    // =================== phase A: all 16 tokens, no barriers ===============
    for (int it = 0; it < NTOK; ++it) {
        float x[16];
        x[0]=xa0.x;  x[1]=xa0.y;  x[2]=xa0.z;  x[3]=xa0.w;
        x[4]=xa1.x;  x[5]=xa1.y;  x[6]=xa1.z;  x[7]=xa1.w;
        x[8]=xa2.x;  x[9]=xa2.y;  x[10]=xa2.z; x[11]=xa2.w;
        x[12]=xa3.x; x[13]=xa3.y; x[14]=xa3.z; x[15]=xa3.w;

        if (it + 1 < NTOK) {   // prefetch next token
            const float* p = p0 + (it + 1) * 1024;
            xa0 = *(const float4*)(p);
            xa1 = *(const float4*)(p + 256);
            xa2 = *(const float4*)(p + 512);
            xa3 = *(const float4*)(p + 768);
        }

        float acc[6] = {0.f, 0.f, 0.f, 0.f, 0.f, 0.f};
        #pragma unroll
        for (int k = 0; k < 16; ++k) {
            const float xv = x[k];
            acc[0] = fmaf(xv, w2r[k][0], acc[0]);
            acc[1] = fmaf(xv, w2r[k][1], acc[1]);
            acc[2] = fmaf(xv, w2r[k][2], acc[2]);
            acc[3] = fmaf(xv, w2r[k][3], acc[3]);
            acc[4] = fmaf(xv, w2r[k][4], acc[4]);
            acc[5] = fmaf(xv, w2r[k][5], acc[5]);
        }
        float r2 = 0.f;
        if (gg == 0) {
            #pragma unroll
            for (int k = 0; k < 16; ++k) r2 = fmaf(x[k], x[k], r2);
        }

        #pragma unroll
        for (int off = 1; off < 64; off <<= 1) {
            acc[0] += __shfl_xor(acc[0], off);
            acc[1] += __shfl_xor(acc[1], off);
            acc[2] += __shfl_xor(acc[2], off);
            acc[3] += __shfl_xor(acc[3], off);
            acc[4] += __shfl_xor(acc[4], off);
            acc[5] += __shfl_xor(acc[5], off);
        }
        if (gg == 0) {
            #pragma unroll
            for (int off = 1; off < 64; off <<= 1) r2 += __shfl_xor(r2, off);
        }

        if (lane == 0) {
            #pragma unroll
            for (int j = 0; j < 6; ++j) Hpart[it][6 * gg + j] = acc[j];
            if (gg == 0) Hpart[it][24] = r2;
        }
    }
    __syncthreads();

    // ====== scalar phase: lanes 0..15 of wave 0, one token per lane ========
    if (tid < NTOK) {
        const int t = tid;
        float Hp[24];
        #pragma unroll
        for (int q = 0; q < 24; ++q) Hp[q] = Hpart[t][q];
        const float r2v = Hpart[t][24];
        const float r_ = 1.0f / (sqrtf(r2v) * 0.03125f + 1e-6f);

        float Hpre[4], Hpost[4], K[16];
        #pragma unroll
        for (int n = 0; n < 4; ++n)
            Hpre[n] = sigmoid_f(fmaf(r_, Hp[n], beta[n]));
        #pragma unroll
        for (int n = 0; n < 4; ++n)
            Hpost[n] = 2.0f * sigmoid_f(fmaf(r_, Hp[4 + n], beta[4 + n]));
        #pragma unroll
        for (int q = 0; q < 16; ++q)
            K[q] = __expf(fmaf(r_, Hp[8 + q], beta[8 + q]));

        float u0=1.f,u1=1.f,u2=1.f,u3=1.f;
        float v0=1.f,v1=1.f,v2=1.f,v3=1.f;
        for (int itr = 0; itr < 10; ++itr) {
            u0 = 1.0f/(K[0]*v0  + K[1]*v1  + K[2]*v2  + K[3]*v3  + 1e-8f);
            u1 = 1.0f/(K[4]*v0  + K[5]*v1  + K[6]*v2  + K[7]*v3  + 1e-8f);
            u2 = 1.0f/(K[8]*v0  + K[9]*v1  + K[10]*v2 + K[11]*v3 + 1e-8f);
            u3 = 1.0f/(K[12]*v0 + K[13]*v1 + K[14]*v2 + K[15]*v3 + 1e-8f);
            v0 = 1.0f/(K[0]*u0  + K[4]*u1  + K[8]*u2  + K[12]*u3 + 1e-8f);
            v1 = 1.0f/(K[1]*u0  + K[5]*u1  + K[9]*u2  + K[13]*u3 + 1e-8f);
            v2 = 1.0f/(K[2]*u0  + K[6]*u1  + K[10]*u2 + K[14]*u3 + 1e-8f);
            v3 = 1.0f/(K[3]*u0  + K[7]*u1  + K[11]*u2 + K[15]*u3 + 1e-8f);
        }
        smalls[t][0] = Hpre[0];  smalls[t][1] = Hpre[1];
        smalls[t][2] = Hpre[2];  smalls[t][3] = Hpre[3];
        smalls[t][4] = Hpost[0]; smalls[t][5] = Hpost[1];
        smalls[t][6] = Hpost[2]; smalls[t][7] = Hpost[3];
        smalls[t][8]  = u0*K[0]*v0;   smalls[t][9]  = u0*K[1]*v1;
        smalls[t][10] = u0*K[2]*v2;   smalls[t][11] = u0*K[3]*v3;
        smalls[t][12] = u1*K[4]*v0;   smalls[t][13] = u1*K[5]*v1;
        smalls[t][14] = u1*K[6]*v2;   smalls[t][15] = u1*K[7]*v3;
        smalls[t][16] = u2*K[8]*v0;   smalls[t][17] = u2*K[9]*v1;
        smalls[t][18] = u2*K[10]*v2;  smalls[t][19] = u2*K[11]*v3;
        smalls[t][20] = u3*K[12]*v0;  smalls[t][21] = u3*K[13]*v1;
        smalls[t][22] = u3*K[14]*v2;  smalls[t][23] = u3*K[15]*v3;
    }
    __syncthreads();

    // ========== phase C: all 16 tokens, 2-deep pipeline, no barriers =======
    // thread(lane,gg): n = gg, d = 4*lane..4*lane+3. Reads are the SAME
    // per-lane addresses phase A touched (L1/L2-hot).
    float4 ca0, ca1, ca2, ca3;   // token it
    float4 cb0, cb1, cb2, cb3;   // token it+1
    {
        const float* p = p0;
        ca0 = *(const float4*)(p);       ca1 = *(const float4*)(p + 256);
        ca2 = *(const float4*)(p + 512); ca3 = *(const float4*)(p + 768);
        const float* q = p0 + 1024;
        cb0 = *(const float4*)(q);       cb1 = *(const float4*)(q + 256);
        cb2 = *(const float4*)(q + 512); cb3 = *(const float4*)(q + 768);
    }

    for (int it = 0; it < NTOK; ++it) {
        const long tok = tok0 + it;

        const float4 xm0 = ca0, xm1 = ca1, xm2 = ca2, xm3 = ca3;
        // rotate pipeline: a <= b, b <= load(it+2)
        ca0 = cb0; ca1 = cb1; ca2 = cb2; ca3 = cb3;
        if (it + 2 < NTOK) {
            const float* p = p0 + (it + 2) * 1024;
            cb0 = *(const float4*)(p);       cb1 = *(const float4*)(p + 256);
            cb2 = *(const float4*)(p + 512); cb3 = *(const float4*)(p + 768);
        }

        const float hp0 = smalls[it][0], hp1 = smalls[it][1];
        const float hp2 = smalls[it][2], hp3 = smalls[it][3];
        const float hpost = smalls[it][4 + gg];
        const float P0 = smalls[it][8 + 4*gg + 0];
        const float P1 = smalls[it][8 + 4*gg + 1];
        const float P2 = smalls[it][8 + 4*gg + 2];
        const float P3 = smalls[it][8 + 4*gg + 3];

        float4 o;
        {
            const float hpre = hp0*xm0.x + hp1*xm1.x + hp2*xm2.x + hp3*xm3.x;
            o.x = fmaf(hpost, hpre, P0*xm0.x + P1*xm1.x + P2*xm2.x + P3*xm3.x);
        }
        {
            const float hpre = hp0*xm0.y + hp1*xm1.y + hp2*xm2.y + hp3*xm3.y;
            o.y = fmaf(hpost, hpre, P0*xm0.y + P1*xm1.y + P2*xm2.y + P3*xm3.y);
        }
        {
            const float hpre = hp0*xm0.z + hp1*xm1.z + hp2*xm2.z + hp3*xm3.z;
            o.z = fmaf(hpost, hpre, P0*xm0.z + P1*xm1.z + P2*xm2.z + P3*xm3.z);
        }
        {
            const float hpre = hp0*xm0.w + hp1*xm1.w + hp2*xm2.w + hp3*xm3.w;
            o.w = fmaf(hpost, hpre, P0*xm0.w + P1*xm1.w + P2*xm2.w + P3*xm3.w);
        }
        *(float4*)(out + tok * 1024 + gg * 256 + 4 * lane) = o;
    }
}

extern "C" void kernel_launch(void* const* d_in, const int* in_sizes, int n_in,
                              void* d_out, int out_size, void* d_ws, size_t ws_size,
                              hipStream_t stream) {
    const float* h     = (const float*)d_in[0];
    const float* nw    = (const float*)d_in[1];
    const float* w     = (const float*)d_in[2];
    const float* alpha = (const float*)d_in[3];
    const float* beta  = (const float*)d_in[4];
    float* out = (float*)d_out;

    mhc_kernel<<<2048, 256, 0, stream>>>(h, nw, w, alpha, beta, out);
}

// Round 8
// 97.516 us; speedup vs baseline: 3.4421x; 1.1604x over previous
//
#include <hip/hip_runtime.h>
#include <math.h>

// ManifoldHyperConnectionFuse on MI355X — R7: VALU path, registers + DPP.
// MFMA abandoned: R6 proved (via on-device calibration) that row/col labels
// were recoverable but H stayed bounded-wrong => A/B operand k-maps differ
// on silicon; not worth 32-probe k-calibration for a 24-wide output.
//
// R2's two real costs, fixed mechanically:
//  1) weight register residency: #pragma unroll 1 on the token loop +
//     per-element asm keep-alive INSIDE the loop (re-load provably illegal).
//  2) reduction: lanes = (ksl 0..15 = 16 consecutive k, ng 0..3 = 6 n's),
//     wave = k-quarter; 16-lane DPP row_ror tree (pure VALU, no DS pipe);
//     4-way cross-wave reduce deferred to one pass after the token loop.
//
// Block: 256 thr (4 waves), 16 tokens, grid 2048.
// Phase A: matvec partials -> Cpart[4][16][28]. 1 barrier.
// Reduce pass (400 jobs). 1 barrier. Scalar phase (lanes 0..15, R2-proven).
// 1 barrier. Phase C (R2-proven fp32).

#define NTOK 16

__device__ __forceinline__ float sigmoid_f(float z) {
    return 1.0f / (1.0f + __expf(-z));
}

// sum over each aligned 16-lane row via DPP row_ror (VALU-only)
__device__ __forceinline__ float row16_sum(float x) {
    x += __int_as_float(__builtin_amdgcn_update_dpp(
        0, __float_as_int(x), 0x121, 0xf, 0xf, false)); // row_ror:1
    x += __int_as_float(__builtin_amdgcn_update_dpp(
        0, __float_as_int(x), 0x122, 0xf, 0xf, false)); // row_ror:2
    x += __int_as_float(__builtin_amdgcn_update_dpp(
        0, __float_as_int(x), 0x124, 0xf, 0xf, false)); // row_ror:4
    x += __int_as_float(__builtin_amdgcn_update_dpp(
        0, __float_as_int(x), 0x128, 0xf, 0xf, false)); // row_ror:8
    return x;
}

__global__ __launch_bounds__(256, 3)
void mhc_kernel(const float* __restrict__ h,
                const float* __restrict__ nw,
                const float* __restrict__ w,
                const float* __restrict__ alpha,
                const float* __restrict__ beta,
                float* __restrict__ out)
{
    const int tid  = threadIdx.x;
    const int lane = tid & 63;
    const int wv   = tid >> 6;     // wave id = k-quarter
    const int ksl  = lane & 15;    // k-slice within quarter (16 consecutive)
    const int ng   = lane >> 4;    // n-group (6 n's each)

    __shared__ float Cpart[4][NTOK][28];  // per-wave partials; [24] = r2 part
    __shared__ float Hpart[NTOK][28];     // reduced H + r2
    __shared__ float smalls[NTOK][26];    // Hpre, Hpost, P

    // ---- fold alpha*nw*w into 96 register weights ----
    // thread covers k in [kbase, kbase+16), n in [6*ng, 6*ng+6)
    const int kbase = 256 * wv + 16 * ksl;
    const float a0 = alpha[0], a1 = alpha[1], a2 = alpha[2];
    float w2r[16][6];
    #pragma unroll
    for (int e = 0; e < 16; ++e) {
        const int k = kbase + e;
        const float nwk = nw[k];
        #pragma unroll
        for (int j = 0; j < 6; ++j) {
            const int n = 6 * ng + j;
            const float as = (n < 4) ? a0 : ((n < 8) ? a1 : a2);
            w2r[e][j] = as * nwk * w[k * 24 + n];
        }
    }

    const long tok0 = (long)blockIdx.x * NTOK;
    const float* pA = h + tok0 * 1024 + kbase;

    // prefetch token 0 (16 consecutive floats)
    float4 xb0 = *(const float4*)(pA + 0);
    float4 xb1 = *(const float4*)(pA + 4);
    float4 xb2 = *(const float4*)(pA + 8);
    float4 xb3 = *(const float4*)(pA + 12);

    // =================== phase A: 16 tokens, no barriers ===================
    #pragma unroll 1
    for (int it = 0; it < NTOK; ++it) {
        float x[16];
        x[0]=xb0.x;  x[1]=xb0.y;  x[2]=xb0.z;  x[3]=xb0.w;
        x[4]=xb1.x;  x[5]=xb1.y;  x[6]=xb1.z;  x[7]=xb1.w;
        x[8]=xb2.x;  x[9]=xb2.y;  x[10]=xb2.z; x[11]=xb2.w;
        x[12]=xb3.x; x[13]=xb3.y; x[14]=xb3.z; x[15]=xb3.w;

        if (it + 1 < NTOK) {    // prefetch next token
            const float* p = pA + (it + 1) * 1024;
            xb0 = *(const float4*)(p + 0);
            xb1 = *(const float4*)(p + 4);
            xb2 = *(const float4*)(p + 8);
            xb3 = *(const float4*)(p + 12);
        }

        // keep w2r pinned in registers: the only def reaching this
        // iteration's FMAs is this opaque asm -> re-load is illegal.
        #pragma unroll
        for (int e = 0; e < 16; ++e)
            #pragma unroll
            for (int j = 0; j < 6; ++j)
                asm volatile("" : "+v"(w2r[e][j]));

        float acc[6] = {0.f, 0.f, 0.f, 0.f, 0.f, 0.f};
        float r2 = 0.f;
        #pragma unroll
        for (int e = 0; e < 16; ++e) {
            const float xv = x[e];
            acc[0] = fmaf(xv, w2r[e][0], acc[0]);
            acc[1] = fmaf(xv, w2r[e][1], acc[1]);
            acc[2] = fmaf(xv, w2r[e][2], acc[2]);
            acc[3] = fmaf(xv, w2r[e][3], acc[3]);
            acc[4] = fmaf(xv, w2r[e][4], acc[4]);
            acc[5] = fmaf(xv, w2r[e][5], acc[5]);
            r2     = fmaf(xv, xv, r2);
        }

        // 16-lane DPP tree: every lane in a row gets the row sum
        acc[0] = row16_sum(acc[0]);
        acc[1] = row16_sum(acc[1]);
        acc[2] = row16_sum(acc[2]);
        acc[3] = row16_sum(acc[3]);
        acc[4] = row16_sum(acc[4]);
        acc[5] = row16_sum(acc[5]);
        r2     = row16_sum(r2);

        if (ksl == 0) {
            #pragma unroll
            for (int j = 0; j < 6; ++j)
                Cpart[wv][it][6 * ng + j] = acc[j];
            if (ng == 0) Cpart[wv][it][24] = r2;  // quarter-r2
        }
    }
    __syncthreads();

    // ---- deferred cross-wave reduce: Hpart[t][c] = sum_w Cpart[w][t][c] ----
    for (int j = tid; j < NTOK * 25; j += 256) {
        const int t = j / 25;
        const int c = j - 25 * t;
        Hpart[t][c] = Cpart[0][t][c] + Cpart[1][t][c] +
                      Cpart[2][t][c] + Cpart[3][t][c];
    }
    __syncthreads();

    // ---- scalar phase: lanes 0..15, one token each (R2-proven) ----
    if (tid < NTOK) {
        const int t = tid;
        float Hp[24];
        #pragma unroll
        for (int q = 0; q < 24; ++q) Hp[q] = Hpart[t][q];
        const float r2v = Hpart[t][24];
        const float r_ = 1.0f / (sqrtf(r2v) * 0.03125f + 1e-6f);

        float Hpre[4], Hpost[4], K[16];
        #pragma unroll
        for (int n = 0; n < 4; ++n)
            Hpre[n] = sigmoid_f(fmaf(r_, Hp[n], beta[n]));
        #pragma unroll
        for (int n = 0; n < 4; ++n)
            Hpost[n] = 2.0f * sigmoid_f(fmaf(r_, Hp[4 + n], beta[4 + n]));
        #pragma unroll
        for (int q = 0; q < 16; ++q)
            K[q] = __expf(fmaf(r_, Hp[8 + q], beta[8 + q]));

        float u0=1.f,u1=1.f,u2=1.f,u3=1.f;
        float v0=1.f,v1=1.f,v2=1.f,v3=1.f;
        for (int itr = 0; itr < 10; ++itr) {
            u0 = 1.0f/(K[0]*v0  + K[1]*v1  + K[2]*v2  + K[3]*v3  + 1e-8f);
            u1 = 1.0f/(K[4]*v0  + K[5]*v1  + K[6]*v2  + K[7]*v3  + 1e-8f);
            u2 = 1.0f/(K[8]*v0  + K[9]*v1  + K[10]*v2 + K[11]*v3 + 1e-8f);
            u3 = 1.0f/(K[12]*v0 + K[13]*v1 + K[14]*v2 + K[15]*v3 + 1e-8f);
            v0 = 1.0f/(K[0]*u0  + K[4]*u1  + K[8]*u2  + K[12]*u3 + 1e-8f);
            v1 = 1.0f/(K[1]*u0  + K[5]*u1  + K[9]*u2  + K[13]*u3 + 1e-8f);
            v2 = 1.0f/(K[2]*u0  + K[6]*u1  + K[10]*u2 + K[14]*u3 + 1e-8f);
            v3 = 1.0f/(K[3]*u0  + K[7]*u1  + K[11]*u2 + K[15]*u3 + 1e-8f);
        }
        smalls[t][0] = Hpre[0];  smalls[t][1] = Hpre[1];
        smalls[t][2] = Hpre[2];  smalls[t][3] = Hpre[3];
        smalls[t][4] = Hpost[0]; smalls[t][5] = Hpost[1];
        smalls[t][6] = Hpost[2]; smalls[t][7] = Hpost[3];
        smalls[t][8]  = u0*K[0]*v0;   smalls[t][9]  = u0*K[1]*v1;
        smalls[t][10] = u0*K[2]*v2;   smalls[t][11] = u0*K[3]*v3;
        smalls[t][12] = u1*K[4]*v0;   smalls[t][13] = u1*K[5]*v1;
        smalls[t][14] = u1*K[6]*v2;   smalls[t][15] = u1*K[7]*v3;
        smalls[t][16] = u2*K[8]*v0;   smalls[t][17] = u2*K[9]*v1;
        smalls[t][18] = u2*K[10]*v2;  smalls[t][19] = u2*K[11]*v3;
        smalls[t][20] = u3*K[12]*v0;  smalls[t][21] = u3*K[13]*v1;
        smalls[t][22] = u3*K[14]*v2;  smalls[t][23] = u3*K[15]*v3;
    }
    __syncthreads();

    // ---- phase C: out = Hpost*h_pre + P@h (R2-proven, fp32) ----
    const int gg = wv;   // n = gg, d = 4*lane..+3
    const float* p0 = h + tok0 * 1024 + 4 * lane;
    float4 ca0, ca1, ca2, ca3, cb0, cb1, cb2, cb3;
    {
        ca0 = *(const float4*)(p0);       ca1 = *(const float4*)(p0 + 256);
        ca2 = *(const float4*)(p0 + 512); ca3 = *(const float4*)(p0 + 768);
        const float* q = p0 + 1024;
        cb0 = *(const float4*)(q);        cb1 = *(const float4*)(q + 256);
        cb2 = *(const float4*)(q + 512);  cb3 = *(const float4*)(q + 768);
    }
    for (int it = 0; it < NTOK; ++it) {
        const long tok = tok0 + it;
        const float4 xm0 = ca0, xm1 = ca1, xm2 = ca2, xm3 = ca3;
        ca0 = cb0; ca1 = cb1; ca2 = cb2; ca3 = cb3;
        if (it + 2 < NTOK) {
            const float* p = p0 + (it + 2) * 1024;
            cb0 = *(const float4*)(p);       cb1 = *(const float4*)(p + 256);
            cb2 = *(const float4*)(p + 512); cb3 = *(const float4*)(p + 768);
        }
        const float hp0 = smalls[it][0], hp1 = smalls[it][1];
        const float hp2 = smalls[it][2], hp3 = smalls[it][3];
        const float hpost = smalls[it][4 + gg];
        const float P0 = smalls[it][8 + 4*gg + 0];
        const float P1 = smalls[it][8 + 4*gg + 1];
        const float P2 = smalls[it][8 + 4*gg + 2];
        const float P3 = smalls[it][8 + 4*gg + 3];

        float4 o;
        {
            const float hpre = hp0*xm0.x + hp1*xm1.x + hp2*xm2.x + hp3*xm3.x;
            o.x = fmaf(hpost, hpre, P0*xm0.x + P1*xm1.x + P2*xm2.x + P3*xm3.x);
        }
        {
            const float hpre = hp0*xm0.y + hp1*xm1.y + hp2*xm2.y + hp3*xm3.y;
            o.y = fmaf(hpost, hpre, P0*xm0.y + P1*xm1.y + P2*xm2.y + P3*xm3.y);
        }
        {
            const float hpre = hp0*xm0.z + hp1*xm1.z + hp2*xm2.z + hp3*xm3.z;
            o.z = fmaf(hpost, hpre, P0*xm0.z + P1*xm1.z + P2*xm2.z + P3*xm3.z);
        }
        {
            const float hpre = hp0*xm0.w + hp1*xm1.w + hp2*xm2.w + hp3*xm3.w;
            o.w = fmaf(hpost, hpre, P0*xm0.w + P1*xm1.w + P2*xm2.w + P3*xm3.w);
        }
        *(float4*)(out + tok * 1024 + gg * 256 + 4 * lane) = o;
    }
}

extern "C" void kernel_launch(void* const* d_in, const int* in_sizes, int n_in,
                              void* d_out, int out_size, void* d_ws, size_t ws_size,
                              hipStream_t stream) {
    const float* h     = (const float*)d_in[0];
    const float* nw    = (const float*)d_in[1];
    const float* w     = (const float*)d_in[2];
    const float* alpha = (const float*)d_in[3];
    const float* beta  = (const float*)d_in[4];
    float* out = (float*)d_out;

    mhc_kernel<<<2048, 256, 0, stream>>>(h, nw, w, alpha, beta, out);
}

// Round 9
// 89.446 us; speedup vs baseline: 3.7527x; 1.0902x over previous
//
#include <hip/hip_runtime.h>
#include <math.h>

// ManifoldHyperConnectionFuse on MI355X — R8: coalesced phase-A loads.
// R7 post-mortem: phase A's per-thread 16-CONSECUTIVE-k layout made every
// float4 load a 16-way cache-line split (16 distinct 64B lines per wave
// instruction). R8 remaps thread k-ownership to
//   k = 256*wv + 64*e + 4*ksl + c   (e=0..3 float4 loads, c=0..3 comps)
// so each load instruction covers ONE contiguous 256B segment (lanes 0-15
// consecutive, ng groups 1-3 broadcast the same segment). Weight fold
// absorbs the k-map; DPP reduce unchanged. Everything else = R7.

#define NTOK 16

__device__ __forceinline__ float sigmoid_f(float z) {
    return 1.0f / (1.0f + __expf(-z));
}

// sum over each aligned 16-lane row via DPP row_ror (VALU-only)
__device__ __forceinline__ float row16_sum(float x) {
    x += __int_as_float(__builtin_amdgcn_update_dpp(
        0, __float_as_int(x), 0x121, 0xf, 0xf, false)); // row_ror:1
    x += __int_as_float(__builtin_amdgcn_update_dpp(
        0, __float_as_int(x), 0x122, 0xf, 0xf, false)); // row_ror:2
    x += __int_as_float(__builtin_amdgcn_update_dpp(
        0, __float_as_int(x), 0x124, 0xf, 0xf, false)); // row_ror:4
    x += __int_as_float(__builtin_amdgcn_update_dpp(
        0, __float_as_int(x), 0x128, 0xf, 0xf, false)); // row_ror:8
    return x;
}

__global__ __launch_bounds__(256, 3)
void mhc_kernel(const float* __restrict__ h,
                const float* __restrict__ nw,
                const float* __restrict__ w,
                const float* __restrict__ alpha,
                const float* __restrict__ beta,
                float* __restrict__ out)
{
    const int tid  = threadIdx.x;
    const int lane = tid & 63;
    const int wv   = tid >> 6;     // wave id = k-quarter
    const int ksl  = lane & 15;    // k-slice within quarter
    const int ng   = lane >> 4;    // n-group (6 n's each)

    __shared__ float Cpart[4][NTOK][28];  // per-wave partials; [24] = r2 part
    __shared__ float Hpart[NTOK][28];     // reduced H + r2
    __shared__ float smalls[NTOK][26];    // Hpre, Hpost, P

    // ---- fold alpha*nw*w into 96 register weights ----
    // thread owns k = 256*wv + 64*e + 4*ksl + c  (e,c in 0..3), n in 6*ng..+6
    const int kqbase = 256 * wv;
    const float a0 = alpha[0], a1 = alpha[1], a2 = alpha[2];
    float w2r[16][6];
    #pragma unroll
    for (int e = 0; e < 4; ++e) {
        #pragma unroll
        for (int c = 0; c < 4; ++c) {
            const int k = kqbase + 64 * e + 4 * ksl + c;
            const float nwk = nw[k];
            #pragma unroll
            for (int j = 0; j < 6; ++j) {
                const int n = 6 * ng + j;
                const float as = (n < 4) ? a0 : ((n < 8) ? a1 : a2);
                w2r[4 * e + c][j] = as * nwk * w[k * 24 + n];
            }
        }
    }

    const long tok0 = (long)blockIdx.x * NTOK;
    const float* pA = h + tok0 * 1024 + kqbase + 4 * ksl;

    // prefetch token 0: 4 coalesced float4 loads (256B segments)
    float4 xb0 = *(const float4*)(pA + 0);
    float4 xb1 = *(const float4*)(pA + 64);
    float4 xb2 = *(const float4*)(pA + 128);
    float4 xb3 = *(const float4*)(pA + 192);

    // =================== phase A: 16 tokens, no barriers ===================
    #pragma unroll 1
    for (int it = 0; it < NTOK; ++it) {
        float x[16];
        x[0]=xb0.x;  x[1]=xb0.y;  x[2]=xb0.z;  x[3]=xb0.w;
        x[4]=xb1.x;  x[5]=xb1.y;  x[6]=xb1.z;  x[7]=xb1.w;
        x[8]=xb2.x;  x[9]=xb2.y;  x[10]=xb2.z; x[11]=xb2.w;
        x[12]=xb3.x; x[13]=xb3.y; x[14]=xb3.z; x[15]=xb3.w;

        if (it + 1 < NTOK) {    // prefetch next token (coalesced)
            const float* p = pA + (it + 1) * 1024;
            xb0 = *(const float4*)(p + 0);
            xb1 = *(const float4*)(p + 64);
            xb2 = *(const float4*)(p + 128);
            xb3 = *(const float4*)(p + 192);
        }

        // keep w2r pinned: only def reaching the FMAs is the asm output
        #pragma unroll
        for (int e = 0; e < 16; ++e)
            #pragma unroll
            for (int j = 0; j < 6; ++j)
                asm volatile("" : "+v"(w2r[e][j]));

        float acc[6] = {0.f, 0.f, 0.f, 0.f, 0.f, 0.f};
        float r2 = 0.f;
        #pragma unroll
        for (int e = 0; e < 16; ++e) {
            const float xv = x[e];
            acc[0] = fmaf(xv, w2r[e][0], acc[0]);
            acc[1] = fmaf(xv, w2r[e][1], acc[1]);
            acc[2] = fmaf(xv, w2r[e][2], acc[2]);
            acc[3] = fmaf(xv, w2r[e][3], acc[3]);
            acc[4] = fmaf(xv, w2r[e][4], acc[4]);
            acc[5] = fmaf(xv, w2r[e][5], acc[5]);
            r2     = fmaf(xv, xv, r2);
        }

        // 16-lane DPP tree: every lane in a row gets the row sum
        acc[0] = row16_sum(acc[0]);
        acc[1] = row16_sum(acc[1]);
        acc[2] = row16_sum(acc[2]);
        acc[3] = row16_sum(acc[3]);
        acc[4] = row16_sum(acc[4]);
        acc[5] = row16_sum(acc[5]);
        r2     = row16_sum(r2);

        if (ksl == 0) {
            #pragma unroll
            for (int j = 0; j < 6; ++j)
                Cpart[wv][it][6 * ng + j] = acc[j];
            if (ng == 0) Cpart[wv][it][24] = r2;  // quarter-r2
        }
    }
    __syncthreads();

    // ---- deferred cross-wave reduce: Hpart[t][c] = sum_w Cpart[w][t][c] ----
    for (int j = tid; j < NTOK * 25; j += 256) {
        const int t = j / 25;
        const int c = j - 25 * t;
        Hpart[t][c] = Cpart[0][t][c] + Cpart[1][t][c] +
                      Cpart[2][t][c] + Cpart[3][t][c];
    }
    __syncthreads();

    // ---- scalar phase: lanes 0..15, one token each (R2-proven) ----
    if (tid < NTOK) {
        const int t = tid;
        float Hp[24];
        #pragma unroll
        for (int q = 0; q < 24; ++q) Hp[q] = Hpart[t][q];
        const float r2v = Hpart[t][24];
        const float r_ = 1.0f / (sqrtf(r2v) * 0.03125f + 1e-6f);

        float Hpre[4], Hpost[4], K[16];
        #pragma unroll
        for (int n = 0; n < 4; ++n)
            Hpre[n] = sigmoid_f(fmaf(r_, Hp[n], beta[n]));
        #pragma unroll
        for (int n = 0; n < 4; ++n)
            Hpost[n] = 2.0f * sigmoid_f(fmaf(r_, Hp[4 + n], beta[4 + n]));
        #pragma unroll
        for (int q = 0; q < 16; ++q)
            K[q] = __expf(fmaf(r_, Hp[8 + q], beta[8 + q]));

        float u0=1.f,u1=1.f,u2=1.f,u3=1.f;
        float v0=1.f,v1=1.f,v2=1.f,v3=1.f;
        for (int itr = 0; itr < 10; ++itr) {
            u0 = 1.0f/(K[0]*v0  + K[1]*v1  + K[2]*v2  + K[3]*v3  + 1e-8f);
            u1 = 1.0f/(K[4]*v0  + K[5]*v1  + K[6]*v2  + K[7]*v3  + 1e-8f);
            u2 = 1.0f/(K[8]*v0  + K[9]*v1  + K[10]*v2 + K[11]*v3 + 1e-8f);
            u3 = 1.0f/(K[12]*v0 + K[13]*v1 + K[14]*v2 + K[15]*v3 + 1e-8f);
            v0 = 1.0f/(K[0]*u0  + K[4]*u1  + K[8]*u2  + K[12]*u3 + 1e-8f);
            v1 = 1.0f/(K[1]*u0  + K[5]*u1  + K[9]*u2  + K[13]*u3 + 1e-8f);
            v2 = 1.0f/(K[2]*u0  + K[6]*u1  + K[10]*u2 + K[14]*u3 + 1e-8f);
            v3 = 1.0f/(K[3]*u0  + K[7]*u1  + K[11]*u2 + K[15]*u3 + 1e-8f);
        }
        smalls[t][0] = Hpre[0];  smalls[t][1] = Hpre[1];
        smalls[t][2] = Hpre[2];  smalls[t][3] = Hpre[3];
        smalls[t][4] = Hpost[0]; smalls[t][5] = Hpost[1];
        smalls[t][6] = Hpost[2]; smalls[t][7] = Hpost[3];
        smalls[t][8]  = u0*K[0]*v0;   smalls[t][9]  = u0*K[1]*v1;
        smalls[t][10] = u0*K[2]*v2;   smalls[t][11] = u0*K[3]*v3;
        smalls[t][12] = u1*K[4]*v0;   smalls[t][13] = u1*K[5]*v1;
        smalls[t][14] = u1*K[6]*v2;   smalls[t][15] = u1*K[7]*v3;
        smalls[t][16] = u2*K[8]*v0;   smalls[t][17] = u2*K[9]*v1;
        smalls[t][18] = u2*K[10]*v2;  smalls[t][19] = u2*K[11]*v3;
        smalls[t][20] = u3*K[12]*v0;  smalls[t][21] = u3*K[13]*v1;
        smalls[t][22] = u3*K[14]*v2;  smalls[t][23] = u3*K[15]*v3;
    }
    __syncthreads();

    // ---- phase C: out = Hpost*h_pre + P@h (R2-proven, fp32) ----
    const int gg = wv;   // n = gg, d = 4*lane..+3
    const float* p0 = h + tok0 * 1024 + 4 * lane;
    float4 ca0, ca1, ca2, ca3, cb0, cb1, cb2, cb3;
    {
        ca0 = *(const float4*)(p0);       ca1 = *(const float4*)(p0 + 256);
        ca2 = *(const float4*)(p0 + 512); ca3 = *(const float4*)(p0 + 768);
        const float* q = p0 + 1024;
        cb0 = *(const float4*)(q);        cb1 = *(const float4*)(q + 256);
        cb2 = *(const float4*)(q + 512);  cb3 = *(const float4*)(q + 768);
    }
    for (int it = 0; it < NTOK; ++it) {
        const long tok = tok0 + it;
        const float4 xm0 = ca0, xm1 = ca1, xm2 = ca2, xm3 = ca3;
        ca0 = cb0; ca1 = cb1; ca2 = cb2; ca3 = cb3;
        if (it + 2 < NTOK) {
            const float* p = p0 + (it + 2) * 1024;
            cb0 = *(const float4*)(p);       cb1 = *(const float4*)(p + 256);
            cb2 = *(const float4*)(p + 512); cb3 = *(const float4*)(p + 768);
        }
        const float hp0 = smalls[it][0], hp1 = smalls[it][1];
        const float hp2 = smalls[it][2], hp3 = smalls[it][3];
        const float hpost = smalls[it][4 + gg];
        const float P0 = smalls[it][8 + 4*gg + 0];
        const float P1 = smalls[it][8 + 4*gg + 1];
        const float P2 = smalls[it][8 + 4*gg + 2];
        const float P3 = smalls[it][8 + 4*gg + 3];

        float4 o;
        {
            const float hpre = hp0*xm0.x + hp1*xm1.x + hp2*xm2.x + hp3*xm3.x;
            o.x = fmaf(hpost, hpre, P0*xm0.x + P1*xm1.x + P2*xm2.x + P3*xm3.x);
        }
        {
            const float hpre = hp0*xm0.y + hp1*xm1.y + hp2*xm2.y + hp3*xm3.y;
            o.y = fmaf(hpost, hpre, P0*xm0.y + P1*xm1.y + P2*xm2.y + P3*xm3.y);
        }
        {
            const float hpre = hp0*xm0.z + hp1*xm1.z + hp2*xm2.z + hp3*xm3.z;
            o.z = fmaf(hpost, hpre, P0*xm0.z + P1*xm1.z + P2*xm2.z + P3*xm3.z);
        }
        {
            const float hpre = hp0*xm0.w + hp1*xm1.w + hp2*xm2.w + hp3*xm3.w;
            o.w = fmaf(hpost, hpre, P0*xm0.w + P1*xm1.w + P2*xm2.w + P3*xm3.w);
        }
        *(float4*)(out + tok * 1024 + gg * 256 + 4 * lane) = o;
    }
}

extern "C" void kernel_launch(void* const* d_in, const int* in_sizes, int n_in,
                              void* d_out, int out_size, void* d_ws, size_t ws_size,
                              hipStream_t stream) {
    const float* h     = (const float*)d_in[0];
    const float* nw    = (const float*)d_in[1];
    const float* w     = (const float*)d_in[2];
    const float* alpha = (const float*)d_in[3];
    const float* beta  = (const float*)d_in[4];
    float* out = (float*)d_out;

    mhc_kernel<<<2048, 256, 0, stream>>>(h, nw, w, alpha, beta, out);
}